// Round 7
// baseline (307.421 us; speedup 1.0000x reference)
//
#include <hip/hip_runtime.h>

// ProtoNet scores, single-GEMM formulation:
//   Z = (X - mean) @ proj            (cols 0..255 of Y)
//   U = (X - mean) @ W, W = proj@P^T (cols 256..511 of Y)  [= Z@P^T exactly]
//   inv = 1/max(||Z||,eps); z2 = ||Z||^2 * inv^2
//   out[n][c] = -sqrt(max(z2 + ||p_c||^2 - 2*U[n][c]*inv, 0))
//
// R12: ledger -- every round's main obeys dur ~= hbm_bytes / 1.2 TB/s with all
// pipes <16%; MFMA-busy pinned at the 13 us floor. Either platform BW ceiling
// or shallow load issue. This round: deep async X staging via global_load_lds
// (raw f32, 8 chunks x 64 KB, double-buffered 128 KB LDS, hardware queue >>
// register staging depth). Swizzle done RIGHT (rule #21): LDS dest linear +
// inverse-swizzled per-lane GLOBAL source + swizzled ds_read (2-way conflicts
// only). f32->bf16 conversion on consume (pack4). Steps barrier-free within a
// chunk; one vmcnt(8)+s_barrier per chunk AFTER own-stage retired (fixes
// R11's cross-wave hazard). Canonical addrspacecast for the LDS operand
// (fixes R11's truncation bug). B reg pipeline + epilogue verbatim R5.

#define DIN     1024
#define NPROTO  256
#define BM      128
#define KT_BYTES 32768                   // 512 cols * 32 k * 2 B per B k-tile
#define SLAB_B  65536                    // 128 rows * 512 B (128 f32) per buffer
#define ROW_OFF (2 * SLAB_B)             // 131072
#define SM_BYTES (ROW_OFF + 3 * BM * 4)  // 132608

// ws layout (bytes); total 1,051,648
#define BBLOB_OFF 0                      // 32 * 32768 = 1048576
#define MVEC_OFF  1048576                // 512 f32: [mean@proj | mean@W]
#define P2_OFF    1050624                // 256 f32

using bf16x8 = __attribute__((ext_vector_type(8))) short;
using f32x4  = __attribute__((ext_vector_type(4))) float;

struct BSet { bf16x8 v[8]; };

__device__ __forceinline__ unsigned f2bf(float f) {
  unsigned u = __float_as_uint(f);
  return (u + 0x7fffu + ((u >> 16) & 1u)) >> 16;
}

__device__ __forceinline__ uint2 pack4(float4 v) {
  return make_uint2(f2bf(v.x) | (f2bf(v.y) << 16), f2bf(v.z) | (f2bf(v.w) << 16));
}

__device__ __forceinline__ bf16x8 mk8(uint2 lo, uint2 hi) {
  union { unsigned u[4]; bf16x8 v; } t;
  t.u[0] = lo.x; t.u[1] = lo.y; t.u[2] = hi.x; t.u[3] = hi.y;
  return t.v;
}

// async global->LDS 16B; canonical addrspacecast (NOT integer truncation)
typedef const __attribute__((address_space(1))) unsigned* gas_ptr;
typedef __attribute__((address_space(3))) unsigned* las_ptr;
__device__ __forceinline__ void gld16(const void* g, void* l) {
  __builtin_amdgcn_global_load_lds((gas_ptr)g, (las_ptr)l, 16, 0, 0);
}

// ---------------------------------------------------------------------------
// Merged prep: 161 blocks x 512 threads (identical to R7-R10, verified).
// ---------------------------------------------------------------------------
__global__ __launch_bounds__(512) void protonet_prep(
    const float* __restrict__ mean, const float* __restrict__ proj,
    const float* __restrict__ protos, unsigned* __restrict__ Bblob,
    float* __restrict__ mvec, float* __restrict__ p2g) {
  __shared__ __align__(16) char SM[37120];
  const int tid = threadIdx.x;
  const int b = blockIdx.x;

  if (b < 32) {
    float* plds = (float*)SM;  // [32][257]
    const int kt = b;
    for (int i = 0; i < 16; ++i) {
      int idx = i * 512 + tid;
      int k = idx >> 8, n = idx & 255;
      plds[k * 257 + n] = proj[(kt * 32 + k) * 256 + n];
    }
    __syncthreads();
    for (int i = 0; i < 8; ++i) {
      int idx = i * 512 + tid;
      int j = idx & 3, lane = (idx >> 2) & 63, nt = (idx >> 8) & 7, w = idx >> 11;
      int l15 = lane & 15, q = lane >> 4;
      int col = w * 128 + nt * 16 + l15;
      int kk = q * 8 + 2 * j;
      unsigned lo = f2bf(plds[kk * 257 + col]);
      unsigned hi = f2bf(plds[(kk + 1) * 257 + col]);
      Bblob[((kt * 4 + w) * 8 + nt) * 256 + lane * 4 + j] = lo | (hi << 16);
    }
  } else if (b < 160) {
    float* plds = (float*)SM;                              // [32][256]
    unsigned short* Wl = (unsigned short*)(SM + 32768);    // [64][33]
    const int ib = b - 32, kt = ib >> 2, c0 = (ib & 3) * 64;
    for (int i = 0; i < 16; ++i) {
      int idx = i * 512 + tid;
      plds[idx] = proj[kt * 32 * 256 + idx];
    }
    __syncthreads();
    const int c = c0 + (tid & 63);
    const int wv = tid >> 6;  // 0..7, each owns 4 k-rows
    float acc4[4] = {0.f, 0.f, 0.f, 0.f};
    const float4* Pr = (const float4*)(protos + c * 256);
    for (int j4 = 0; j4 < 64; ++j4) {
      float4 pv = Pr[j4];
#pragma unroll
      for (int i = 0; i < 4; ++i) {
        const float4 pj = *(const float4*)&plds[(wv * 4 + i) * 256 + j4 * 4];
        acc4[i] += pj.x * pv.x + pj.y * pv.y + pj.z * pv.z + pj.w * pv.w;
      }
    }
#pragma unroll
    for (int i = 0; i < 4; ++i)
      Wl[(c - c0) * 33 + wv * 4 + i] = (unsigned short)f2bf(acc4[i]);
    __syncthreads();
    for (int i = 0; i < 2; ++i) {
      int idx = i * 512 + tid;
      int j = idx & 3, q = (idx >> 2) & 3, r = idx >> 4;
      int gc = c0 + r;
      int w = 2 + (gc >> 7);
      int cw = gc & 127;
      int nt = cw >> 4, l15 = cw & 15;
      int lane = q * 16 + l15;
      int kk = q * 8 + 2 * j;
      unsigned lo = Wl[r * 33 + kk], hi = Wl[r * 33 + kk + 1];
      Bblob[((kt * 4 + w) * 8 + nt) * 256 + lane * 4 + j] = lo | (hi << 16);
    }
  } else {
    float* meanl  = (float*)SM;            // 1024 f
    float* red    = (float*)(SM + 4096);   // 512 f
    float* red2   = (float*)(SM + 6144);   // 512 f
    float* mprojl = (float*)(SM + 8192);   // 256 f
    meanl[tid] = mean[tid];
    meanl[tid + 512] = mean[tid + 512];
    __syncthreads();
    {
      const int n = tid & 255, half = tid >> 8;
      float s = 0.f;
      const int k0 = half * 512;
#pragma unroll 8
      for (int k = k0; k < k0 + 512; ++k) s += meanl[k] * proj[k * 256 + n];
      red[tid] = s;
    }
    __syncthreads();
    if (tid < 256) {
      float m = red[tid] + red[tid + 256];
      mvec[tid] = m;
      mprojl[tid] = m;
    }
    __syncthreads();
    {
      const int c = tid & 255, half = tid >> 8;
      const float4* Pr = (const float4*)(protos + c * 256);
      float sw = 0.f, sp = 0.f;
      const int j0 = half * 32;
#pragma unroll 4
      for (int j4 = j0; j4 < j0 + 32; ++j4) {
        float4 pv = Pr[j4];
        const float4 mj = *(const float4*)&mprojl[j4 * 4];
        sw += mj.x * pv.x + mj.y * pv.y + mj.z * pv.z + mj.w * pv.w;
        sp += pv.x * pv.x + pv.y * pv.y + pv.z * pv.z + pv.w * pv.w;
      }
      red[tid] = sw;
      red2[tid] = sp;
    }
    __syncthreads();
    if (tid < 256) {
      mvec[256 + tid] = red[tid] + red[tid + 256];
      p2g[tid] = red2[tid] + red2[tid + 256];
    }
  }
}

// ---------------------------------------------------------------------------
// main: 256 blocks x 512 thr, BM=128. X staged f32 via global_load_lds in
// 8 chunks of 128 k (64 KB), double-buffered. LDS layout: linear 1-KB blocks
// (rows 2J,2J+1); content XOR-swizzled via per-lane global src:
//   LDS[lr*512 + c'*16] holds X[row0+lr][chunk c' ^ (lr&7)]  (16-B chunks)
// Read: chunk c at lr*512 + ((c ^ (lr&7))*16)  -> 2 lanes/bank (free).
// Wave (wr=wave>>2, wc=wave&3): rows [64*wr,+64), cols [128*wc,+128) of [Z|U].
// ---------------------------------------------------------------------------
__global__ __launch_bounds__(512, 2) void protonet_main(
    const float* __restrict__ X, const unsigned* __restrict__ Bblob,
    const float* __restrict__ mvec, const float* __restrict__ p2g,
    float* __restrict__ out) {
  __shared__ __align__(16) char SM[SM_BYTES];
  float* rowsum = (float*)(SM + ROW_OFF);
  float* rowinv = rowsum + BM;
  float* rowz2  = rowsum + 2 * BM;

  const int tid = threadIdx.x;
  const int wave = tid >> 6;
  const int wc = wave & 3;               // column group
  const int wr = wave >> 2;              // row half
  const int lane = tid & 63;
  const int l15 = lane & 15;
  const int q = lane >> 4;
  const int row0 = blockIdx.x * BM;
  const int cn = wc * 128;
  const int rbase = wr * 64;

  if (tid < BM) rowsum[tid] = 0.f;

  const char* Bb = (const char*)Bblob + wc * 8192 + lane * 16;

  f32x4 acc[4][8];
#pragma unroll
  for (int mt = 0; mt < 4; ++mt)
#pragma unroll
    for (int nt = 0; nt < 8; ++nt) acc[mt][nt] = (f32x4){0.f, 0.f, 0.f, 0.f};

  // stage chunk ch (128 f32/row) into slab p: 8 x 1-KB blocks per wave
  auto stage = [&](int p, int ch) {
#pragma unroll
    for (int j = 0; j < 8; ++j) {
      const int J = wave * 8 + j;               // 1-KB block (wave-uniform)
      const int lr = 2 * J + (lane >> 5);       // per-lane row 0..127
      const int k4 = (lane & 31) ^ (lr & 7);    // inverse-swizzled src chunk
      const float* g = X + (size_t)(row0 + lr) * DIN + ch * 128 + k4 * 4;
      gld16(g, SM + p * SLAB_B + J * 1024);
    }
  };

  // one 32-k step: A frags from slab p (chunk-local step s), B from bs regs;
  // then reload bs with B(tnext).
  auto step = [&](int p, int s, BSet& bs, int tnext) {
    const char* Sb = SM + p * SLAB_B;
    bf16x8 af[4];
#pragma unroll
    for (int mt = 0; mt < 4; ++mt) {
      int lr = rbase + mt * 16 + l15;
      int sw = lr & 7;
      int c0 = s * 8 + q * 2;
      float4 fa = *(const float4*)(Sb + lr * 512 + ((c0 ^ sw) * 16));
      float4 fb = *(const float4*)(Sb + lr * 512 + (((c0 + 1) ^ sw) * 16));
      af[mt] = mk8(pack4(fa), pack4(fb));
    }
#pragma unroll
    for (int mt = 0; mt < 4; ++mt)
#pragma unroll
      for (int nt = 0; nt < 8; ++nt)
        acc[mt][nt] = __builtin_amdgcn_mfma_f32_16x16x32_bf16(af[mt], bs.v[nt],
                                                              acc[mt][nt], 0, 0, 0);
    const char* bsrc = Bb + tnext * KT_BYTES;
#pragma unroll
    for (int nt = 0; nt < 8; ++nt) bs.v[nt] = *(const bf16x8*)(bsrc + nt * 1024);
  };

  // ---- prologue: B(0),B(1) to regs; stage chunk 0 -> slab 0; full drain ----
  BSet BA, BB;
#pragma unroll
  for (int nt = 0; nt < 8; ++nt) BA.v[nt] = *(const bf16x8*)(Bb + nt * 1024);
#pragma unroll
  for (int nt = 0; nt < 8; ++nt)
    BB.v[nt] = *(const bf16x8*)(Bb + KT_BYTES + nt * 1024);
  stage(0, 0);
  asm volatile("s_waitcnt vmcnt(0) lgkmcnt(0)\n\ts_barrier" ::: "memory");

  // ---- 8 chunks x 4 steps; barrier-free inside a chunk ----
  int p = 0;
  for (int ch = 0; ch < 8; ++ch) {
    if (ch < 7) {
      stage(p ^ 1, ch + 1);
      asm volatile("" ::: "memory");
    }
    const int t0 = ch * 4;
    step(p, 0, BA, t0 + 2 <= 31 ? t0 + 2 : 31);
    step(p, 1, BB, t0 + 3 <= 31 ? t0 + 3 : 31);
    step(p, 2, BA, t0 + 4 <= 31 ? t0 + 4 : 31);
    step(p, 3, BB, t0 + 5 <= 31 ? t0 + 5 : 31);
    if (ch < 7) {
      // own stage(ch+1) retired (<=8 newest B reloads may stay in flight),
      // THEN barrier -> all waves' staging visible next chunk.
      asm volatile("s_waitcnt vmcnt(8)\n\ts_barrier" ::: "memory");
      p ^= 1;
    }
  }

  // ---- epilogue: center, row norms (wc<2 waves hold Z), scores (wc>=2) ----
#pragma unroll
  for (int nt = 0; nt < 8; ++nt) {
    float mv = mvec[cn + nt * 16 + l15];
#pragma unroll
    for (int mt = 0; mt < 4; ++mt)
#pragma unroll
      for (int r = 0; r < 4; ++r) acc[mt][nt][r] -= mv;
  }

  if (wc < 2) {
#pragma unroll
    for (int mt = 0; mt < 4; ++mt)
#pragma unroll
      for (int r = 0; r < 4; ++r) {
        float ss = 0.f;
#pragma unroll
        for (int nt = 0; nt < 8; ++nt) ss += acc[mt][nt][r] * acc[mt][nt][r];
        ss += __shfl_xor(ss, 1);
        ss += __shfl_xor(ss, 2);
        ss += __shfl_xor(ss, 4);
        ss += __shfl_xor(ss, 8);
        if (l15 == 0) atomicAdd(&rowsum[rbase + mt * 16 + q * 4 + r], ss);
      }
  }
  __syncthreads();
  if (tid < BM) {
    float s = rowsum[tid];
    float inv = 1.0f / fmaxf(sqrtf(s), 1e-12f);
    rowinv[tid] = inv;
    rowz2[tid] = s * inv * inv;
  }
  __syncthreads();

  if (wc >= 2) {
#pragma unroll
    for (int nt = 0; nt < 8; ++nt) {
      int col = cn - 256 + nt * 16 + l15;
      float pp = p2g[col];
#pragma unroll
      for (int mt = 0; mt < 4; ++mt)
#pragma unroll
        for (int r = 0; r < 4; ++r) {
          int row = rbase + mt * 16 + q * 4 + r;
          float d2 = rowz2[row] + pp - 2.0f * acc[mt][nt][r] * rowinv[row];
          float sc = -sqrtf(fmaxf(d2, 0.f));
          __builtin_nontemporal_store(sc, &out[(row0 + row) * NPROTO + col]);
        }
    }
  }
}

extern "C" void kernel_launch(void* const* d_in, const int* in_sizes, int n_in,
                              void* d_out, int out_size, void* d_ws, size_t ws_size,
                              hipStream_t stream) {
  const float* X = (const float*)d_in[0];
  const float* mean = (const float*)d_in[1];
  const float* proj = (const float*)d_in[2];
  const float* protos = (const float*)d_in[3];
  float* out = (float*)d_out;

  char* ws = (char*)d_ws;  // uses 1,051,648 B
  unsigned* Bblob = (unsigned*)(ws + BBLOB_OFF);
  float* mvec = (float*)(ws + MVEC_OFF);
  float* p2 = (float*)(ws + P2_OFF);

  hipLaunchKernelGGL(protonet_prep, dim3(161), dim3(512), 0, stream,
                     mean, proj, protos, Bblob, mvec, p2);
  hipLaunchKernelGGL(protonet_main, dim3(256), dim3(512), 0, stream,
                     X, Bblob, mvec, p2, out);
}